// Round 2
// baseline (217.538 us; speedup 1.0000x reference)
//
#include <hip/hip_runtime.h>

#define NCH    40
#define MORD   16
#define NR     17
#define NBINS  257

// ---------------- compile-time table generation (double precision) ----------------
namespace cfg {

constexpr double PI  = 3.14159265358979323846264338327950288;
constexpr double LN2 = 0.693147180559945309417232121458176568;

constexpr double cexp(double x) {
    double t = 1.0, s = 1.0;
    for (int i = 1; i < 40; ++i) { t *= x / i; s += t; }
    return s;
}

constexpr double clog(double z) {
    double lg = 0.0;
    while (z > 1.4142135623730951) { z *= 0.5; lg += LN2; }
    while (z < 0.7071067811865476) { z *= 2.0; lg -= LN2; }
    double u = (z - 1.0) / (z + 1.0), u2 = u * u, t = u, s = u;
    for (int k = 1; k < 24; ++k) { t *= u2; s += t / (2.0 * k + 1.0); }
    return lg + 2.0 * s;
}

constexpr double ccos(double x) {
    double tp = 2.0 * PI;
    double q = x / tp;
    long long k = (long long)(q + (q >= 0.0 ? 0.5 : -0.5));
    double r = x - (double)k * tp;
    double r2 = r * r, t = 1.0, s = 1.0;
    for (int i = 1; i < 20; ++i) { t *= -r2 / ((2.0 * i - 1.0) * (2.0 * i)); s += t; }
    return s;
}

constexpr double csin(double x) { return ccos(x - PI / 2.0); }

struct Tab {
    int   start[43];     // start[c] = first bin with t_b > c
    int   chan[257];     // segment id c(b), 0..40
    float w[257];        // t_b - c(b), in [0,1)
    float eql[NCH];
    float lift[NR];
    float ctf[NR][21];   // folded cosine: r[l] = sum_j ctf[l][j]*(ys[j] +- ys[41-j])
    constexpr Tab() : start(), chan(), w(), eql(), lift(), ctf() {
        const double lmax  = clog(87.0 / 7.0);
        const double U1127 = lmax / 41.0;
        for (int c = 0; c <= 41; ++c) {
            double thr = 22.4 * (cexp((double)c * U1127) - 1.0);
            int s = (int)thr + 1;
            if (s < 1) s = 1;
            if (s > 256) s = 256;
            start[c] = s;
        }
        start[42] = start[41];
        for (int c = 0; c <= 40; ++c) {
            for (int b = start[c]; b < start[c + 1]; ++b) {
                double mel = 1127.0 * clog(1.0 + (double)b * 31.25 / 700.0);
                double t   = mel / (1127.0 * U1127);
                w[b] = (float)(t - (double)c);
                chan[b] = c;
            }
        }
        for (int c = 0; c < NCH; ++c) {
            double cf = 700.0 * (cexp((double)(c + 1) * U1127) - 1.0);
            double f2 = cf * cf;
            double e  = f2 / (f2 + 160000.0);
            e = e * e * (f2 + 1440000.0) / (f2 + 9610000.0);
            eql[c] = (float)e;
        }
        for (int m = 0; m < NR; ++m)
            lift[m] = (float)(1.0 + 11.0 * csin(PI * (double)m / 22.0));
        lift[0] = 2.0f;
        for (int l = 0; l < NR; ++l)
            for (int j = 0; j <= 20; ++j) {
                double s = (j == 0) ? 1.0 : 2.0;
                ctf[l][j] = (float)(s * ccos(PI * (double)(j * l) / 41.0) / 82.0);
            }
    }
};

constexpr Tab T{};

} // namespace cfg

// ---- filterbank over one frame via ALIGNED float4 loads + static realignment ----
// Caller guarantees (fg*257 + 1) & 3 == S, so word B = fg*257+1-S is 16B-aligned.
// Elements are consumed as v[(k+S)>>2].[(k+S)&3] -- pure register naming, no shuffles.
template<int S>
__device__ __forceinline__ void fbank_path(const float* __restrict__ x,
                                           long long fg, float fb[NCH])
{
    using cfg::T;
    const long long B = fg * 257 + 1 - S;
    const float4* p4 = reinterpret_cast<const float4*>(x + B);
    float4 a = p4[0];
    #pragma unroll
    for (int j = 0; j < 64; ++j) {
        float4 b;
        if (S > 0 || j < 63) b = p4[j + 1]; else b = a;   // compile-time resolved
        float e0, e1, e2, e3;
        if      (S == 0) { e0 = a.x; e1 = a.y; e2 = a.z; e3 = a.w; }
        else if (S == 1) { e0 = a.y; e1 = a.z; e2 = a.w; e3 = b.x; }
        else if (S == 2) { e0 = a.z; e1 = a.w; e2 = b.x; e3 = b.y; }
        else             { e0 = a.w; e1 = b.x; e2 = b.y; e3 = b.z; }
        const float ee[4] = { e0, e1, e2, e3 };
        #pragma unroll
        for (int q = 0; q < 4; ++q) {
            const int   bb = 4 * j + 1 + q;               // bin 1..256
            const int   ch = T.chan[bb];
            const float wa = T.w[bb];
            if (ch < NCH) fb[ch]     = fmaf(wa, ee[q], fb[ch]);
            if (ch >= 1)  fb[ch - 1] = fmaf(1.0f - wa, ee[q], fb[ch - 1]);
        }
        a = b;
    }
}

// One thread = one frame. Waves are partitioned by frame residue class mod 4 so the
// global misalignment shift is wave-uniform and compile-time: no LDS, no barriers.
__global__ __launch_bounds__(256, 2) void plp_kernel(const float* __restrict__ x,
                                                     float* __restrict__ out,
                                                     int nframes)
{
    using cfg::T;
    const int tid  = threadIdx.x;
    const int lane = tid & 63;
    const long long GW = (long long)blockIdx.x * 4 + (tid >> 6);  // global wave id
    const int       r  = (int)(GW & 3);                           // residue class
    const long long q  = GW >> 2;
    const long long fg = (long long)r + 4 * (q * 64 + lane);
    if (fg >= nframes) return;

    float fb[NCH];
    #pragma unroll
    for (int c = 0; c < NCH; ++c) fb[c] = 0.f;

    // S = (fg*257+1)&3 = (r+1)&3  (wave-uniform switch; lanes never diverge)
    switch (r) {
        case 0:  fbank_path<1>(x, fg, fb); break;
        case 1:  fbank_path<2>(x, fg, fb); break;
        case 2:  fbank_path<3>(x, fg, fb); break;
        default: fbank_path<0>(x, fg, fb); break;
    }

    // ---- equal-loudness + cube-root compression (fast log/exp), ys in regs ----
    float yv[NCH];
    #pragma unroll
    for (int c = 0; c < NCH; ++c) {
        float v = fmaxf(fb[c], 1e-5f) * T.eql[c];
        yv[c] = __expf(0.33f * __logf(v));
    }

    // ---- even/odd fold of y (42 taps incl. duplicated edges) ----
    float ye[21], yo[21];
    ye[0] = yv[0] + yv[39];  yo[0] = yv[0] - yv[39];       // ys[0], ys[41]
    #pragma unroll
    for (int jj = 1; jj <= 20; ++jj) {
        float aa = yv[jj - 1], bb = yv[40 - jj];           // ys[j], ys[41-j]
        ye[jj] = aa + bb;  yo[jj] = aa - bb;
    }

    // ---- folded cosine transform: 17 lags x 21 taps, literal coefficients ----
    float rr[NR];
    #pragma unroll
    for (int lg = 0; lg < NR; ++lg) {
        const float* yy = (lg & 1) ? yo : ye;
        float acc = 0.f;
        #pragma unroll
        for (int jj = 0; jj <= 20; ++jj) acc = fmaf(T.ctf[lg][jj], yy[jj], acc);
        rr[lg] = acc;
    }

    // ---- Levinson-Durbin (unrolled, v_rcp) ----
    float a[MORD];
    #pragma unroll
    for (int i = 0; i < MORD; ++i) a[i] = 0.f;
    float E = rr[0];
    #pragma unroll
    for (int i = 1; i <= MORD; ++i) {
        float acc = rr[i];
        #pragma unroll
        for (int jj = 0; jj < i - 1; ++jj) acc = fmaf(a[jj], rr[i - 1 - jj], acc);
        float k = -acc * __builtin_amdgcn_rcpf(E);
        const int half = (i - 1) / 2;
        #pragma unroll
        for (int jj = 0; jj < half; ++jj) {
            float t1 = a[jj], t2 = a[i - 2 - jj];
            a[jj]         = fmaf(k, t2, t1);
            a[i - 2 - jj] = fmaf(k, t1, t2);
        }
        if ((i - 1) & 1) a[half] = fmaf(k, a[half], a[half]);
        a[i - 1] = k;
        E = E * (1.f - k * k);
    }

    // ---- cepstrum (c[0] unused; ccs[k]=k*cc[k] keeps inner fma literal-free) ----
    float cc[NR], ccs[NR];
    #pragma unroll
    for (int m = 1; m <= MORD; ++m) {
        float acc = 0.f;
        #pragma unroll
        for (int k2 = 1; k2 < m; ++k2)
            acc = fmaf(ccs[k2], a[m - k2 - 1], acc);
        float cm = -(a[m - 1] + acc * (1.0f / (float)m));
        cc[m]  = cm;
        ccs[m] = (float)m * cm;
    }

    // ---- direct stores: out + fg*16 is 64B-aligned; thread's 4x float4 cover a
    // ---- full contiguous 64B line -> L2 write-combines cleanly, no staging needed.
    float o[16];
    #pragma unroll
    for (int m = 1; m <= MORD; ++m) o[m - 1] = cc[m] * T.lift[m];

    float4* op = reinterpret_cast<float4*>(out + (size_t)fg * 16);
    op[0] = make_float4(o[0],  o[1],  o[2],  o[3]);
    op[1] = make_float4(o[4],  o[5],  o[6],  o[7]);
    op[2] = make_float4(o[8],  o[9],  o[10], o[11]);
    op[3] = make_float4(o[12], o[13], o[14], o[15]);
}

extern "C" void kernel_launch(void* const* d_in, const int* in_sizes, int n_in,
                              void* d_out, int out_size, void* d_ws, size_t ws_size,
                              hipStream_t stream) {
    const float* x   = (const float*)d_in[0];
    float*      outp = (float*)d_out;
    int nframes = in_sizes[0] / NBINS;                 // 131072
    int nblocks = (nframes + 255) / 256;               // 512 blocks x 4 waves = 2048 waves
    plp_kernel<<<nblocks, 256, 0, stream>>>(x, outp, nframes);
}

// Round 3
// 201.204 us; speedup vs baseline: 1.0812x; 1.0812x over previous
//
#include <hip/hip_runtime.h>

#define NCH    40
#define MORD   16
#define NR     17
#define NBINS  257
#define NCHUNK 8                 // 8 chunks x 32 bins = bins 0..255
#define CB     32                // bins per chunk
#define PAIRW  65                // LDS words per frame-pair row (64 data + 1 pad)

// ---------------- compile-time table generation (double precision) ----------------
namespace cfg {

constexpr double PI  = 3.14159265358979323846264338327950288;
constexpr double LN2 = 0.693147180559945309417232121458176568;

constexpr double cexp(double x) {
    double t = 1.0, s = 1.0;
    for (int i = 1; i < 40; ++i) { t *= x / i; s += t; }
    return s;
}

constexpr double clog(double z) {
    double lg = 0.0;
    while (z > 1.4142135623730951) { z *= 0.5; lg += LN2; }
    while (z < 0.7071067811865476) { z *= 2.0; lg -= LN2; }
    double u = (z - 1.0) / (z + 1.0), u2 = u * u, t = u, s = u;
    for (int k = 1; k < 24; ++k) { t *= u2; s += t / (2.0 * k + 1.0); }
    return lg + 2.0 * s;
}

constexpr double ccos(double x) {
    double tp = 2.0 * PI;
    double q = x / tp;
    long long k = (long long)(q + (q >= 0.0 ? 0.5 : -0.5));
    double r = x - (double)k * tp;
    double r2 = r * r, t = 1.0, s = 1.0;
    for (int i = 1; i < 20; ++i) { t *= -r2 / ((2.0 * i - 1.0) * (2.0 * i)); s += t; }
    return s;
}

constexpr double csin(double x) { return ccos(x - PI / 2.0); }

struct Tab {
    int   start[43];     // start[c] = first bin with t_b > c
    int   chan[257];     // segment id c(b), 0..40
    float w[257];        // t_b - c(b), in [0,1)
    float eql[NCH];
    float lift[NR];
    float ctf[NR][21];   // folded cosine: r[l] = sum_j ctf[l][j]*(ys[j] +- ys[41-j])
    constexpr Tab() : start(), chan(), w(), eql(), lift(), ctf() {
        const double lmax  = clog(87.0 / 7.0);
        const double U1127 = lmax / 41.0;
        for (int c = 0; c <= 41; ++c) {
            double thr = 22.4 * (cexp((double)c * U1127) - 1.0);
            int s = (int)thr + 1;
            if (s < 1) s = 1;
            if (s > 256) s = 256;
            start[c] = s;
        }
        start[42] = start[41];
        for (int c = 0; c <= 40; ++c) {
            for (int b = start[c]; b < start[c + 1]; ++b) {
                double mel = 1127.0 * clog(1.0 + (double)b * 31.25 / 700.0);
                double t   = mel / (1127.0 * U1127);
                w[b] = (float)(t - (double)c);
                chan[b] = c;
            }
        }
        for (int c = 0; c < NCH; ++c) {
            double cf = 700.0 * (cexp((double)(c + 1) * U1127) - 1.0);
            double f2 = cf * cf;
            double e  = f2 / (f2 + 160000.0);
            e = e * e * (f2 + 1440000.0) / (f2 + 9610000.0);
            eql[c] = (float)e;
        }
        for (int m = 0; m < NR; ++m)
            lift[m] = (float)(1.0 + 11.0 * csin(PI * (double)m / 22.0));
        lift[0] = 2.0f;
        for (int l = 0; l < NR; ++l)
            for (int j = 0; j <= 20; ++j) {
                double s = (j == 0) ? 1.0 : 2.0;
                ctf[l][j] = (float)(s * ccos(PI * (double)(j * l) / 41.0) / 82.0);
            }
    }
};

constexpr Tab T{};

} // namespace cfg

// async global->LDS DMA, 4 bytes/lane, linear LDS dest (wave-uniform base + lane*4)
__device__ __forceinline__ void gload_lds4(const float* g, float* l) {
    __builtin_amdgcn_global_load_lds(
        (const __attribute__((address_space(1))) unsigned int*)g,
        (__attribute__((address_space(3))) unsigned int*)l, 4, 0, 0);
}

// Per-wave self-contained double-buffered staging: wave w owns slab[w]. Each wave's
// lanes only read words staged by the SAME wave -> no __syncthreads anywhere; the
// only waits are counted per-wave vmcnt (prefetch of next chunk stays in flight).
// LDS word (r*65 + half*32 + p) -> bank (r+p)&31, exactly 2 lanes/bank = free.
__global__ __launch_bounds__(256, 2) void plp_kernel(const float* __restrict__ x,
                                                     float* __restrict__ out,
                                                     int nframes)
{
    using cfg::T;
    __shared__ float slab[4][2][32][PAIRW];      // 66560 B -> 2 blocks/CU, 8 waves/CU

    const int tid = threadIdx.x;
    const int w   = tid >> 6;                    // wave 0..3
    const int l   = tid & 63;
    const int s   = l >> 5;                      // frame parity within pair row
    const int j   = l & 31;                      // bin-in-chunk lane
    const long long F0    = (long long)blockIdx.x * 256;
    const long long fbase = F0 + (long long)(w << 6);   // this wave's 64 frames

    // stage chunk c (bins 32c..32c+31) of this wave's 64 frames into buffer b
    auto stage = [&](int c, int b) {
        asm volatile("" ::: "memory");           // pin prior LDS reads before DMA issue
        const float* gp0 = x + c * CB + j;
        #pragma unroll
        for (int r = 0; r < 32; ++r) {           // pair row r hosts frames 2r, 2r+1
            long long fg = fbase + 2 * r + s;
            if (fg > (long long)nframes - 1) fg = (long long)nframes - 1;
            gload_lds4(gp0 + fg * NBINS, &slab[w][b][r][0]);
        }
    };

    float fb[NCH];
    #pragma unroll
    for (int c = 0; c < NCH; ++c) fb[c] = 0.f;

    stage(0, 0);                                 // 32 loads in flight

    // ---- barrier-free double-buffered sparse mel filterbank (fp32) ----
    #pragma unroll
    for (int c8 = 0; c8 < NCHUNK; ++c8) {
        if (c8 + 1 < NCHUNK) {
            stage(c8 + 1, (c8 + 1) & 1);         // 64 in flight (chunk c oldest)
            asm volatile("s_waitcnt vmcnt(32)" ::: "memory");  // chunk c landed
        } else {
            asm volatile("s_waitcnt vmcnt(0)" ::: "memory");   // last chunk
        }
        const float* fr = &slab[w][c8 & 1][l >> 1][(l & 1) * CB];
        #pragma unroll
        for (int p = 0; p < CB; ++p) {
            const int bb = (c8 << 5) + p;        // bin 0..255 (bin 0 has weight 0)
            if (bb == 0) continue;
            const float xv = fr[p];
            const int   ch = T.chan[bb];
            const float wa = T.w[bb];
            if (ch < NCH) fb[ch]     = fmaf(wa, xv, fb[ch]);
            if (ch >= 1)  fb[ch - 1] = fmaf(1.0f - wa, xv, fb[ch - 1]);
        }
    }

    const long long frame = F0 + tid;
    const bool live = frame < (long long)nframes;

    // ---- equal-loudness + cube-root compression (fast log/exp), ys in regs ----
    float yv[NCH];
    #pragma unroll
    for (int c = 0; c < NCH; ++c) {
        float v = fmaxf(fb[c], 1e-5f) * T.eql[c];
        yv[c] = __expf(0.33f * __logf(v));
    }

    // ---- even/odd fold of y (42 taps incl. duplicated edges) ----
    float ye[21], yo[21];
    ye[0] = yv[0] + yv[39];  yo[0] = yv[0] - yv[39];       // ys[0], ys[41]
    #pragma unroll
    for (int jj = 1; jj <= 20; ++jj) {
        float aa = yv[jj - 1], bb = yv[40 - jj];           // ys[j], ys[41-j]
        ye[jj] = aa + bb;  yo[jj] = aa - bb;
    }

    // ---- folded cosine transform: 17 lags x 21 taps, literal coefficients ----
    float rr[NR];
    #pragma unroll
    for (int lg = 0; lg < NR; ++lg) {
        const float* yy = (lg & 1) ? yo : ye;
        float acc = 0.f;
        #pragma unroll
        for (int jj = 0; jj <= 20; ++jj) acc = fmaf(T.ctf[lg][jj], yy[jj], acc);
        rr[lg] = acc;
    }

    // ---- Levinson-Durbin (unrolled, v_rcp) ----
    float a[MORD];
    #pragma unroll
    for (int i = 0; i < MORD; ++i) a[i] = 0.f;
    float E = rr[0];
    #pragma unroll
    for (int i = 1; i <= MORD; ++i) {
        float acc = rr[i];
        #pragma unroll
        for (int jj = 0; jj < i - 1; ++jj) acc = fmaf(a[jj], rr[i - 1 - jj], acc);
        float k = -acc * __builtin_amdgcn_rcpf(E);
        const int half = (i - 1) / 2;
        #pragma unroll
        for (int jj = 0; jj < half; ++jj) {
            float t1 = a[jj], t2 = a[i - 2 - jj];
            a[jj]         = fmaf(k, t2, t1);
            a[i - 2 - jj] = fmaf(k, t1, t2);
        }
        if ((i - 1) & 1) a[half] = fmaf(k, a[half], a[half]);
        a[i - 1] = k;
        E = E * (1.f - k * k);
    }

    // ---- cepstrum (c[0] unused; ccs[k]=k*cc[k] keeps inner fma literal-free) ----
    float cc[NR], ccs[NR];
    #pragma unroll
    for (int m = 1; m <= MORD; ++m) {
        float acc = 0.f;
        #pragma unroll
        for (int k2 = 1; k2 < m; ++k2)
            acc = fmaf(ccs[k2], a[m - k2 - 1], acc);
        float cm = -(a[m - 1] + acc * (1.0f / (float)m));
        cc[m]  = cm;
        ccs[m] = (float)m * cm;
    }

    // ---- direct stores: thread's 4x float4 cover its frame's full 64B line ----
    if (live) {
        float o[16];
        #pragma unroll
        for (int m = 1; m <= MORD; ++m) o[m - 1] = cc[m] * T.lift[m];

        float4* op = reinterpret_cast<float4*>(out + (size_t)frame * 16);
        op[0] = make_float4(o[0],  o[1],  o[2],  o[3]);
        op[1] = make_float4(o[4],  o[5],  o[6],  o[7]);
        op[2] = make_float4(o[8],  o[9],  o[10], o[11]);
        op[3] = make_float4(o[12], o[13], o[14], o[15]);
    }
}

extern "C" void kernel_launch(void* const* d_in, const int* in_sizes, int n_in,
                              void* d_out, int out_size, void* d_ws, size_t ws_size,
                              hipStream_t stream) {
    const float* x   = (const float*)d_in[0];
    float*      outp = (float*)d_out;
    int nframes = in_sizes[0] / NBINS;                 // 131072
    int nblocks = (nframes + 255) / 256;               // 512 = 2 blocks/CU, all resident
    plp_kernel<<<nblocks, 256, 0, stream>>>(x, outp, nframes);
}

// Round 4
// 196.321 us; speedup vs baseline: 1.1081x; 1.0249x over previous
//
#include <hip/hip_runtime.h>
#include <hip/hip_fp16.h>

#define NCH    40
#define MORD   16
#define NR     17
#define NBINS  257
#define FPB    128               // frames per block = threads per block (2 waves)

// ---------------- compile-time table generation (double precision) ----------------
namespace cfg {

constexpr double PI  = 3.14159265358979323846264338327950288;
constexpr double LN2 = 0.693147180559945309417232121458176568;

constexpr double cexp(double x) {
    double t = 1.0, s = 1.0;
    for (int i = 1; i < 40; ++i) { t *= x / i; s += t; }
    return s;
}

constexpr double clog(double z) {
    double lg = 0.0;
    while (z > 1.4142135623730951) { z *= 0.5; lg += LN2; }
    while (z < 0.7071067811865476) { z *= 2.0; lg -= LN2; }
    double u = (z - 1.0) / (z + 1.0), u2 = u * u, t = u, s = u;
    for (int k = 1; k < 24; ++k) { t *= u2; s += t / (2.0 * k + 1.0); }
    return lg + 2.0 * s;
}

constexpr double ccos(double x) {
    double tp = 2.0 * PI;
    double q = x / tp;
    long long k = (long long)(q + (q >= 0.0 ? 0.5 : -0.5));
    double r = x - (double)k * tp;
    double r2 = r * r, t = 1.0, s = 1.0;
    for (int i = 1; i < 20; ++i) { t *= -r2 / ((2.0 * i - 1.0) * (2.0 * i)); s += t; }
    return s;
}

constexpr double csin(double x) { return ccos(x - PI / 2.0); }

struct Tab {
    int   start[43];     // start[c] = first bin with t_b > c
    int   chan[257];     // segment id c(b), 0..40  (chan[0]=0,w[0]=0 and chan[256]=0,w[256]=0 -> pruned)
    float w[257];        // t_b - c(b), in [0,1)
    float eql[NCH];
    float lift[NR];
    float ctf[NR][21];   // folded cosine: r[l] = sum_j ctf[l][j]*(ys[j] +- ys[41-j])
    constexpr Tab() : start(), chan(), w(), eql(), lift(), ctf() {
        const double lmax  = clog(87.0 / 7.0);
        const double U1127 = lmax / 41.0;
        for (int c = 0; c <= 41; ++c) {
            double thr = 22.4 * (cexp((double)c * U1127) - 1.0);
            int s = (int)thr + 1;
            if (s < 1) s = 1;
            if (s > 256) s = 256;
            start[c] = s;
        }
        start[42] = start[41];
        for (int c = 0; c <= 40; ++c) {
            for (int b = start[c]; b < start[c + 1]; ++b) {
                double mel = 1127.0 * clog(1.0 + (double)b * 31.25 / 700.0);
                double t   = mel / (1127.0 * U1127);
                w[b] = (float)(t - (double)c);
                chan[b] = c;
            }
        }
        for (int c = 0; c < NCH; ++c) {
            double cf = 700.0 * (cexp((double)(c + 1) * U1127) - 1.0);
            double f2 = cf * cf;
            double e  = f2 / (f2 + 160000.0);
            e = e * e * (f2 + 1440000.0) / (f2 + 9610000.0);
            eql[c] = (float)e;
        }
        for (int m = 0; m < NR; ++m)
            lift[m] = (float)(1.0 + 11.0 * csin(PI * (double)m / 22.0));
        lift[0] = 2.0f;
        for (int l = 0; l < NR; ++l)
            for (int j = 0; j <= 20; ++j) {
                double s = (j == 0) ? 1.0 : 2.0;
                ctf[l][j] = (float)(s * ccos(PI * (double)(j * l) / 41.0) / 82.0);
            }
    }
};

constexpr Tab T{};

} // namespace cfg

// ---- filterbank over 128 half2 pairs; PAR=0: bins (2p,2p+1), PAR=1: bins (2p+1,2p+2).
// ---- All weights/channels are compile-time literals; zero-weight edge bins pruned.
template<int PAR>
__device__ __forceinline__ void fbank_pairs(const __half2* __restrict__ fr2, float fb[NCH])
{
    using cfg::T;
    #pragma unroll
    for (int p = 0; p < 128; ++p) {
        const float2 xp = __half22float2(fr2[p]);
        {
            const int   bb = 2 * p + PAR;
            const int   ch = T.chan[bb];
            const float wa = T.w[bb];
            if (wa != 0.f || ch != 0) {                 // constant-folded per p
                if (ch < NCH) fb[ch]     = fmaf(wa, xp.x, fb[ch]);
                if (ch >= 1)  fb[ch - 1] = fmaf(1.0f - wa, xp.x, fb[ch - 1]);
            }
        }
        {
            const int   bb = 2 * p + 1 + PAR;
            const int   ch = T.chan[bb];
            const float wa = T.w[bb];
            if (wa != 0.f || ch != 0) {
                if (ch < NCH) fb[ch]     = fmaf(wa, xp.y, fb[ch]);
                if (ch >= 1)  fb[ch - 1] = fmaf(1.0f - wa, xp.y, fb[ch - 1]);
            }
        }
    }
}

// Two-phase R0 structure with linear 16B-aligned staging:
//  - stage: block's 128 frames are contiguous & float4-aligned (F0*257*4 % 16 == 0);
//    64 rounds of global dwordx4 -> 2x cvt_pk -> ds_write_b64 at byte 8i. Identity
//    layout (no pad): 257 is odd -> read banks spiral (l+p)&31, exact 2-way = free.
//  - compute: wave 0 owns even frames (aligned pairs 2p,2p+1), wave 1 odd frames
//    (aligned pairs 2p+1,2p+2). Wave-uniform branch, literal weights on both paths.
__global__ __launch_bounds__(FPB) void plp_kernel(const float* __restrict__ x,
                                                  float* __restrict__ out,
                                                  int nframes)
{
    using cfg::T;
    __shared__ __half slabH[FPB * NBINS];        // 65792 B -> 2 blocks/CU

    const int tid = threadIdx.x;
    const long long F0 = (long long)blockIdx.x * FPB;

    // ---- linear coalesced staging: 8224 float4s = 128 frames x 257 floats ----
    {
        const float4* src = reinterpret_cast<const float4*>(x + F0 * NBINS);
        #pragma unroll 8
        for (int r = 0; r < 64; ++r) {
            const int i = (r << 7) + tid;        // float4 index within slab
            const float4 v = src[i];
            union { __half2 h[2]; uint2 u; } cv;
            cv.h[0] = __float22half2_rn(make_float2(v.x, v.y));
            cv.h[1] = __float22half2_rn(make_float2(v.z, v.w));
            *reinterpret_cast<uint2*>(&slabH[(size_t)4 * i]) = cv.u;   // byte 8i, b64
        }
        if (tid < 32) {                          // tail: 8224 - 64*128 = 32
            const int i = 8192 + tid;
            const float4 v = src[i];
            union { __half2 h[2]; uint2 u; } cv;
            cv.h[0] = __float22half2_rn(make_float2(v.x, v.y));
            cv.h[1] = __float22half2_rn(make_float2(v.z, v.w));
            *reinterpret_cast<uint2*>(&slabH[(size_t)4 * i]) = cv.u;
        }
    }
    __syncthreads();

    const int w  = tid >> 6;                     // 0: even frames, 1: odd frames
    const int l  = tid & 63;
    const int fl = 2 * l + w;                    // local frame 0..127
    const long long frame = F0 + fl;

    // base half index fl*257 + w is even for both parities -> 4B-aligned half2 reads
    const __half2* fr2 = reinterpret_cast<const __half2*>(&slabH[fl * NBINS + w]);

    float fb[NCH];
    #pragma unroll
    for (int c = 0; c < NCH; ++c) fb[c] = 0.f;

    if (w == 0) fbank_pairs<0>(fr2, fb);
    else        fbank_pairs<1>(fr2, fb);

    // ---- equal-loudness + cube-root compression (fast log/exp), ys in regs ----
    float yv[NCH];
    #pragma unroll
    for (int c = 0; c < NCH; ++c) {
        float v = fmaxf(fb[c], 1e-5f) * T.eql[c];
        yv[c] = __expf(0.33f * __logf(v));
    }

    // ---- even/odd fold of y (42 taps incl. duplicated edges) ----
    float ye[21], yo[21];
    ye[0] = yv[0] + yv[39];  yo[0] = yv[0] - yv[39];       // ys[0], ys[41]
    #pragma unroll
    for (int jj = 1; jj <= 20; ++jj) {
        float aa = yv[jj - 1], bb = yv[40 - jj];           // ys[j], ys[41-j]
        ye[jj] = aa + bb;  yo[jj] = aa - bb;
    }

    // ---- folded cosine transform: 17 lags x 21 taps, literal coefficients ----
    float rr[NR];
    #pragma unroll
    for (int lg = 0; lg < NR; ++lg) {
        const float* yy = (lg & 1) ? yo : ye;
        float acc = 0.f;
        #pragma unroll
        for (int jj = 0; jj <= 20; ++jj) acc = fmaf(T.ctf[lg][jj], yy[jj], acc);
        rr[lg] = acc;
    }

    // ---- Levinson-Durbin (unrolled, v_rcp) ----
    float a[MORD];
    #pragma unroll
    for (int i = 0; i < MORD; ++i) a[i] = 0.f;
    float E = rr[0];
    #pragma unroll
    for (int i = 1; i <= MORD; ++i) {
        float acc = rr[i];
        #pragma unroll
        for (int jj = 0; jj < i - 1; ++jj) acc = fmaf(a[jj], rr[i - 1 - jj], acc);
        float k = -acc * __builtin_amdgcn_rcpf(E);
        const int half = (i - 1) / 2;
        #pragma unroll
        for (int jj = 0; jj < half; ++jj) {
            float t1 = a[jj], t2 = a[i - 2 - jj];
            a[jj]         = fmaf(k, t2, t1);
            a[i - 2 - jj] = fmaf(k, t1, t2);
        }
        if ((i - 1) & 1) a[half] = fmaf(k, a[half], a[half]);
        a[i - 1] = k;
        E = E * (1.f - k * k);
    }

    // ---- cepstrum (c[0] unused; ccs[k]=k*cc[k] keeps inner fma literal-free) ----
    float cc[NR], ccs[NR];
    #pragma unroll
    for (int m = 1; m <= MORD; ++m) {
        float acc = 0.f;
        #pragma unroll
        for (int k2 = 1; k2 < m; ++k2)
            acc = fmaf(ccs[k2], a[m - k2 - 1], acc);
        float cm = -(a[m - 1] + acc * (1.0f / (float)m));
        cc[m]  = cm;
        ccs[m] = (float)m * cm;
    }

    // ---- direct stores: thread's 4x float4 cover its frame's full 64B line ----
    if (frame < (long long)nframes) {
        float o[16];
        #pragma unroll
        for (int m = 1; m <= MORD; ++m) o[m - 1] = cc[m] * T.lift[m];

        float4* op = reinterpret_cast<float4*>(out + (size_t)frame * 16);
        op[0] = make_float4(o[0],  o[1],  o[2],  o[3]);
        op[1] = make_float4(o[4],  o[5],  o[6],  o[7]);
        op[2] = make_float4(o[8],  o[9],  o[10], o[11]);
        op[3] = make_float4(o[12], o[13], o[14], o[15]);
    }
}

extern "C" void kernel_launch(void* const* d_in, const int* in_sizes, int n_in,
                              void* d_out, int out_size, void* d_ws, size_t ws_size,
                              hipStream_t stream) {
    const float* x   = (const float*)d_in[0];
    float*      outp = (float*)d_out;
    int nframes = in_sizes[0] / NBINS;                 // 131072 (multiple of FPB)
    int nblocks = (nframes + FPB - 1) / FPB;           // 1024 blocks, 2 resident/CU
    plp_kernel<<<nblocks, FPB, 0, stream>>>(x, outp, nframes);
}